// Round 6
// baseline (3257.240 us; speedup 1.0000x reference)
//
#include <hip/hip_runtime.h>
#include <hip/hip_bf16.h>

#define BB 256      // batch
#define CC 2048     // code_num
#define HD 1024     // hidden
#define TT 64       // max_len
#define H3 3072
#define NBLK 256
#define NGRP 8      // groups of batch rows
#define GBLK 32     // blocks per group
#define GROWS 32    // batch rows per group

typedef __attribute__((ext_vector_type(8))) short bf16x8;
typedef __attribute__((ext_vector_type(4))) float f32x4;
typedef __attribute__((ext_vector_type(4))) int   i32x4;

__device__ __forceinline__ float sigmoidf_(float x){ return 1.0f/(1.0f+__expf(-x)); }
__device__ __forceinline__ float tanhf_(float x){ float e=__expf(2.0f*x); return 1.0f - 2.0f/(e+1.0f); }
__device__ __forceinline__ bf16x8 ldfrag(const __hip_bfloat16* p){
  return *reinterpret_cast<const bf16x8*>(p);
}
__device__ __forceinline__ unsigned short bfbits(float x){
  __hip_bfloat16 b = __float2bfloat16(x);
  return *reinterpret_cast<unsigned short*>(&b);
}
__device__ __forceinline__ void st_sys_bf16(__hip_bfloat16* p, float v){
  __hip_atomic_store((unsigned short*)p, bfbits(v), __ATOMIC_RELAXED, __HIP_MEMORY_SCOPE_SYSTEM);
}
// 16B system-coherent load. Must waitv0() before consuming.
__device__ __forceinline__ i32x4 ld_sys16(const void* p){
  i32x4 r;
  asm volatile("global_load_dwordx4 %0, %1, off sc0 sc1"
               : "=v"(r) : "v"(p) : "memory");
  return r;
}
__device__ __forceinline__ void waitv0(){
  asm volatile("s_waitcnt vmcnt(0)" ::: "memory");
  __builtin_amdgcn_sched_barrier(0);
}

__global__ void cvt_f32_bf16(const float* __restrict__ in, __hip_bfloat16* __restrict__ out, int n){
  int i = (blockIdx.x*blockDim.x + threadIdx.x)*4;
  int stride = gridDim.x*blockDim.x*4;
  for (; i < n; i += stride){
    float4 v = *reinterpret_cast<const float4*>(in + i);
    ushort4 s;
    s.x = bfbits(v.x); s.y = bfbits(v.y); s.z = bfbits(v.z); s.w = bfbits(v.w);
    *reinterpret_cast<ushort4*>(out + i) = s;
  }
}

#define MFMA(a,b,c) __builtin_amdgcn_mfma_f32_16x16x32_bf16((a),(b),(c),0,0,0)

struct St4 { i32x4 r0, r1, r2, r3; };

// Persistent GRU. 256 blocks x 1024 threads (16 waves), 1 block/CU.
// Each block self-assigns a slot = (xcd, q, g) at startup by reading its
// physical XCC_ID and CAS-claiming from its own XCD's pool, so the 4 weight
// slices (bsub = xcd*4+q, ~704KB each -> 2.8MB) are shared by all 32 blocks
// of that XCD and stay L2-resident across all 64 steps. Groups (g = batch-row
// partition) span XCDs; activation exchange via sc0sc1 (L3-coherent) ops.
__global__ __launch_bounds__(1024, 4) void gru_persistent(
    const __hip_bfloat16* __restrict__ wih,     // [3H][C]
    const __hip_bfloat16* __restrict__ whh,     // [3H][H]
    const __hip_bfloat16* __restrict__ wout,    // [C][H]
    const __hip_bfloat16* __restrict__ noise16, // [B][H]
    const float* __restrict__ bih,
    const float* __restrict__ bhh,
    const float* __restrict__ bout,
    float* __restrict__ samples,                // [B][T][C]
    float* __restrict__ hiddens,                // [B][T][H]
    __hip_bfloat16* cA, __hip_bfloat16* cB,     // [B][C] codes ping-pong
    __hip_bfloat16* hA, __hip_bfloat16* hB,     // [B][H] h ping-pong
    unsigned* flagA, unsigned* flagB,
    unsigned* xcdTicket, unsigned* slotClaim)
{
  // LDS: 64KB codes k-half + 64KB h + 27KB gate exchange = 155KB
  __shared__ __align__(16) char bufC[65536];   // [32 rows][1024 bf16], swizzled
  __shared__ __align__(16) char bufH[65536];   // [32 rows][1024 bf16], swizzled
  __shared__ float eplA[12*64*9];              // 12 waves x 64 lanes x 9 (8 used)
  __shared__ int s_slot;

  const int tid  = threadIdx.x;
  const int lane = tid & 63;
  const int wid  = tid >> 6;      // 0..15
  const int rl   = lane & 15;
  const int kg   = lane >> 4;

  // ---- XCD-affine slot self-assignment ----
  if (tid == 0){
    unsigned xcd;
    asm volatile("s_getreg_b32 %0, hwreg(20, 0, 4)" : "=s"(xcd));  // HW_REG_XCC_ID
    xcd &= 7u;
    int slot = -1;
    unsigned tkt = atomicAdd(&xcdTicket[xcd], 1u);
    if (tkt < 32u){
      int s = (int)(xcd*32u + tkt);
      if (atomicCAS(&slotClaim[s], 0u, 1u) == 0u) slot = s;
    }
    while (slot < 0){
      for (int s = 0; s < NBLK && slot < 0; s++){
        if (atomicCAS(&slotClaim[s], 0u, 1u) == 0u) slot = s;
      }
    }
    s_slot = slot;
  }
  __syncthreads();
  const int slot = s_slot;
  const int g    = slot & 7;                       // group (batch rows)
  const int bsub = (slot >> 5)*4 + ((slot & 31) >> 3);   // column-slice id

  // ---- group flag barrier (monotonic generations) ----
  auto signal = [&](unsigned* flags, unsigned gen){
    __syncthreads();   // all waves' stores drained (vmcnt0) before flag
    if (tid == 0)
      __hip_atomic_store(&flags[g*GBLK + bsub], gen, __ATOMIC_RELAXED, __HIP_MEMORY_SCOPE_SYSTEM);
  };
  auto waitf = [&](unsigned* flags, unsigned gen){
    if (tid < GBLK){
      while (__hip_atomic_load(&flags[g*GBLK + tid], __ATOMIC_RELAXED, __HIP_MEMORY_SCOPE_SYSTEM) < gen)
        __builtin_amdgcn_s_sleep(4);
    }
    __syncthreads();
  };

  // ---- staging: 64KB = 4096 x 16B chunks, 4 per thread ----
  auto issue4 = [&](const __hip_bfloat16* src, int rowStride, int colBase)->St4{
    St4 s;
    {
      int ci = tid;        int row = ci>>7, c = ci&127;
      s.r0 = ld_sys16(src + (size_t)(g*GROWS+row)*rowStride + colBase + c*8);
    }{
      int ci = tid+1024;   int row = ci>>7, c = ci&127;
      s.r1 = ld_sys16(src + (size_t)(g*GROWS+row)*rowStride + colBase + c*8);
    }{
      int ci = tid+2048;   int row = ci>>7, c = ci&127;
      s.r2 = ld_sys16(src + (size_t)(g*GROWS+row)*rowStride + colBase + c*8);
    }{
      int ci = tid+3072;   int row = ci>>7, c = ci&127;
      s.r3 = ld_sys16(src + (size_t)(g*GROWS+row)*rowStride + colBase + c*8);
    }
    return s;
  };
  auto write4 = [&](char* buf, const St4& s){
    {
      int ci = tid;        int row = ci>>7, c = ci&127;
      *(i32x4*)(buf + row*2048 + ((c ^ (row&7))<<4)) = s.r0;
    }{
      int ci = tid+1024;   int row = ci>>7, c = ci&127;
      *(i32x4*)(buf + row*2048 + ((c ^ (row&7))<<4)) = s.r1;
    }{
      int ci = tid+2048;   int row = ci>>7, c = ci&127;
      *(i32x4*)(buf + row*2048 + ((c ^ (row&7))<<4)) = s.r2;
    }{
      int ci = tid+3072;   int row = ci>>7, c = ci&127;
      *(i32x4*)(buf + row*2048 + ((c ^ (row&7))<<4)) = s.r3;
    }
  };
  auto ldsfrag = [&](const char* buf, int row, int c)->bf16x8{
    return *(const bf16x8*)(buf + row*2048 + ((c ^ (row&7))<<4));
  };

  // ---------------- phase A: GRU cell -> h_t ----------------
  auto phaseA = [&](const __hip_bfloat16* codesCur, const __hip_bfloat16* hprev,
                    __hip_bfloat16* hnext, int t, bool first){
    St4 sh, sc0, sc1;
    if (!first) sh = issue4(hprev, HD, 0);
    sc0 = issue4(codesCur, CC, 0);
    waitv0();
    if (!first) write4(bufH, sh);
    write4(bufC, sc0);
    sc1 = issue4(codesCur, CC, 1024);   // k-half 1, lands during compute-1
    __syncthreads();

    const bool act = (wid < 12);
    f32x4 accI = {0.f,0.f,0.f,0.f};   // ih part
    f32x4 accH = {0.f,0.f,0.f,0.f};   // hh part
    int mt=0, ar=0;
    const __hip_bfloat16 *wr_ih = nullptr, *wr_hh = nullptr;
    if (act){
      mt = wid & 1;
      int u = wid >> 1, gate = u % 3, hjt = u / 3;
      ar = mt*16 + rl;
      size_t jW = (size_t)(gate*HD + bsub*32 + hjt*16 + rl);
      wr_ih = wih + jW*CC + kg*8;
      wr_hh = whh + jW*HD + kg*8;
      if (!first){
#pragma unroll 8
        for (int k = 0; k < 1024; k += 32){
          int c = (k>>3) + kg;
          accH = MFMA(ldsfrag(bufH, ar, c), ldfrag(wr_hh + k), accH);
        }
      }
#pragma unroll 8
      for (int k = 0; k < 1024; k += 32){
        int c = (k>>3) + kg;
        accI = MFMA(ldsfrag(bufC, ar, c), ldfrag(wr_ih + k), accI);
      }
    }
    __syncthreads();          // bufC k-half0 consumed by all
    waitv0();                 // sc1 arrived
    write4(bufC, sc1);
    __syncthreads();
    if (act){
#pragma unroll 8
      for (int k = 0; k < 1024; k += 32){
        int c = (k>>3) + kg;
        accI = MFMA(ldsfrag(bufC, ar, c), ldfrag(wr_ih + 1024 + k), accI);
      }
      float* p = &eplA[(wid*64 + lane)*9];
      *(f32x4*)p       = accI;
      *(f32x4*)(p + 4) = accH;
    }
    __syncthreads();

    if (wid < 4){
      const int mt2 = wid & 1, hj2 = wid >> 1;
      const int jG  = bsub*32 + hj2*16 + rl;     // H column
      // writer wid = mt + 2*(gate + 3*hj)
      const float* pR = &eplA[(((mt2 + 2*(0 + 3*hj2)))*64 + lane)*9];
      const float* pZ = &eplA[(((mt2 + 2*(1 + 3*hj2)))*64 + lane)*9];
      const float* pN = &eplA[(((mt2 + 2*(2 + 3*hj2)))*64 + lane)*9];
      const float bir = bih[jG], biz = bih[jG+HD], bin = bih[jG+2*HD];
      const float bhr = bhh[jG], bhz = bhh[jG+HD], bhn = bhh[jG+2*HD];
#pragma unroll
      for (int q = 0; q < 4; q++){
        const int lr   = mt2*16 + kg*4 + q;      // local row
        const int brow = g*GROWS + lr;
        float r = sigmoidf_(pR[q] + pR[4+q] + bir + bhr);
        float z = sigmoidf_(pZ[q] + pZ[4+q] + biz + bhz);
        float n = tanhf_(pN[q] + bin + r*(pN[4+q] + bhn));
        float hp = 0.0f;
        if (!first){
          int c = jG >> 3;
          const __hip_bfloat16* hb = (const __hip_bfloat16*)
            (bufH + lr*2048 + ((c ^ (lr&7))<<4) + (jG&7)*2);
          hp = __bfloat162float(*hb);
        }
        float hv = (1.0f - z)*n + z*hp;
        __builtin_nontemporal_store(hv, &hiddens[(size_t)brow*TT*HD + (size_t)t*HD + jG]);
        st_sys_bf16(hnext + (size_t)brow*HD + jG, hv);
      }
    }
  };

  // ---------------- phase B: codes_t = sigmoid(act @ Wout^T + b) ----------
  auto phaseB = [&](const __hip_bfloat16* actSrc, __hip_bfloat16* codesDst, int t){
    St4 sh = issue4(actSrc, HD, 0);
    waitv0();
    write4(bufH, sh);
    __syncthreads();
    if (wid < 8){
      const int mt = wid & 1, cj = wid >> 1;
      const int ar = mt*16 + rl;
      const int ca = bsub*64 + cj*16 + rl;
      const __hip_bfloat16* wrow = wout + (size_t)ca*HD + kg*8;
      f32x4 acc = {0.f,0.f,0.f,0.f};
#pragma unroll 8
      for (int k = 0; k < 1024; k += 32){
        int c = (k>>3) + kg;
        acc = MFMA(ldsfrag(bufH, ar, c), ldfrag(wrow + k), acc);
      }
      const float b0 = bout[ca];
#pragma unroll
      for (int q = 0; q < 4; q++){
        const int brow = g*GROWS + mt*16 + kg*4 + q;
        float s0 = sigmoidf_(acc[q] + b0);
        __builtin_nontemporal_store(s0, &samples[(size_t)brow*TT*CC + (size_t)t*CC + ca]);
        st_sys_bf16(codesDst + (size_t)brow*CC + ca, s0);
      }
    }
  };

  // ---------------- sequence ----------------
  phaseB(noise16, cA, 0);              // samples[:,0,:], codes_0 -> cA
  signal(flagB, 1u);

#pragma unroll 1
  for (int t = 0; t < TT; t++){
    const __hip_bfloat16* codesCur = (t & 1) ? cB : cA;   // codes_t
    const __hip_bfloat16* hprev    = (t & 1) ? hA : hB;   // h_{t-1}
    __hip_bfloat16* hnext          = (t & 1) ? hB : hA;   // h_t
    waitf(flagB, (unsigned)(t+1));
    phaseA(codesCur, hprev, hnext, t, t == 0);
    signal(flagA, (unsigned)(t+1));
    if (t < TT-1){
      waitf(flagA, (unsigned)(t+1));
      phaseB(hnext, (t & 1) ? cA : cB, t+1);              // codes_{t+1}
      signal(flagB, (unsigned)(t+2));
    }
  }
}

extern "C" void kernel_launch(void* const* d_in, const int* in_sizes, int n_in,
                              void* d_out, int out_size, void* d_ws, size_t ws_size,
                              hipStream_t stream) {
  const float* noise = (const float*)d_in[0];
  const float* W_ih  = (const float*)d_in[1];
  const float* b_ih  = (const float*)d_in[2];
  const float* W_hh  = (const float*)d_in[3];
  const float* b_hh  = (const float*)d_in[4];
  const float* W_out = (const float*)d_in[5];
  const float* b_out = (const float*)d_in[6];

  float* samples = (float*)d_out;                       // [B][T][C]
  float* hiddens = samples + (size_t)BB*TT*CC;          // [B][T][H]

  char* w = (char*)d_ws;
  unsigned* flagA   = (unsigned*)w;            w += 1024;   // 256 u32
  unsigned* flagB   = (unsigned*)w;            w += 1024;
  unsigned* xcdTick = (unsigned*)w;            w += 256;    // 8 u32 (+pad)
  unsigned* slotClm = (unsigned*)w;            w += 1024;   // 256 u32
  __hip_bfloat16* wih16 = (__hip_bfloat16*)w;  w += (size_t)H3*CC*2;
  __hip_bfloat16* whh16 = (__hip_bfloat16*)w;  w += (size_t)H3*HD*2;
  __hip_bfloat16* wout16= (__hip_bfloat16*)w;  w += (size_t)CC*HD*2;
  __hip_bfloat16* noise16=(__hip_bfloat16*)w;  w += (size_t)BB*HD*2;
  __hip_bfloat16* cA    = (__hip_bfloat16*)w;  w += (size_t)BB*CC*2;
  __hip_bfloat16* cB    = (__hip_bfloat16*)w;  w += (size_t)BB*CC*2;
  __hip_bfloat16* hA    = (__hip_bfloat16*)w;  w += (size_t)BB*HD*2;
  __hip_bfloat16* hB    = (__hip_bfloat16*)w;  w += (size_t)BB*HD*2;

  hipMemsetAsync(flagA, 0, 1024+1024+256+1024, stream);  // flags+tickets+claims
  cvt_f32_bf16<<<2048, 256, 0, stream>>>(W_ih,  wih16,  H3*CC);
  cvt_f32_bf16<<<2048, 256, 0, stream>>>(W_hh,  whh16,  H3*HD);
  cvt_f32_bf16<<<1024, 256, 0, stream>>>(W_out, wout16, CC*HD);
  cvt_f32_bf16<<<256,  256, 0, stream>>>(noise, noise16, BB*HD);

  gru_persistent<<<NBLK, 1024, 0, stream>>>(
      wih16, whh16, wout16, noise16, b_ih, b_hh, b_out,
      samples, hiddens, cA, cB, hA, hB, flagA, flagB, xcdTick, slotClm);
}